// Round 5
// baseline (565.071 us; speedup 1.0000x reference)
//
#include <hip/hip_runtime.h>
#include <hip/hip_bf16.h>

typedef __attribute__((ext_vector_type(8))) short short8;
typedef __attribute__((ext_vector_type(4))) float f32x4;
typedef unsigned short u16;
typedef unsigned int u32;

#define NORM_INV (1.0f / 100.0f)

__device__ __forceinline__ float silu(float x) {
    return x * __builtin_amdgcn_rcpf(1.0f + __expf(-x));
}

__device__ __forceinline__ u16 f2bf(float x) {
    union { float f; u32 u; } v; v.f = x;
    u32 r = v.u + 0x7fff + ((v.u >> 16) & 1);   // RNE
    return (u16)(r >> 16);
}

__device__ __forceinline__ float bflo(u32 u) {
    union { u32 u; float f; } v; v.u = u << 16; return v.f;
}
__device__ __forceinline__ float bfhi(u32 u) {
    union { u32 u; float f; } v; v.u = u & 0xffff0000u; return v.f;
}

// ---------------- kernel 0: weight transposes (tiny) ----------------
__global__ void prep_weights(const float* __restrict__ W1, const float* __restrict__ W2,
                             u16* __restrict__ W1abT, u16* __restrict__ W2T) {
    int idx = blockIdx.x * blockDim.x + threadIdx.x;
    if (idx < 256 * 128) {
        int j = idx >> 7, k = idx & 127;
        float v = (j < 128) ? W1[k * 128 + j] : W1[(128 + k) * 128 + (j - 128)];
        W1abT[j * 128 + k] = f2bf(v);
    } else if (idx < 256 * 128 + 128 * 128) {
        int t = idx - 256 * 128;
        int n = t >> 7, k = t & 127;
        W2T[n * 128 + k] = f2bf(W2[k * 128 + n]);
    }
}

// ---------------- kernel 1: AB[node][256] = [h@W1a + b1 | h@W1b] ----------------
__global__ __launch_bounds__(256) void ab_kernel(const float* __restrict__ h,
        const float* __restrict__ b1, const u16* __restrict__ W1abT,
        u16* __restrict__ AB, int N) {
    __shared__ u16 hs[32 * 128];     // 32 nodes x 128 k, bf16, XOR-swizzled
    int tid = threadIdx.x;
    int n0 = blockIdx.x * 32;
    int lane = tid & 63, wave = tid >> 6;

    #pragma unroll
    for (int it = 0; it < 8; ++it) {
        int item = it * 256 + tid;          // 2048 items, 2 k each
        int m = item >> 6;
        int k = (item & 63) * 2;
        float2 hv = make_float2(0.f, 0.f);
        if (n0 + m < N) hv = *(const float2*)(h + (size_t)(n0 + m) * 128 + k);
        u32 pk = (u32)f2bf(hv.x) | ((u32)f2bf(hv.y) << 16);
        int byteoff = m * 256 + ((k * 2) ^ ((m & 7) << 4));
        *(u32*)((char*)hs + byteoff) = pk;
    }

    short8 bw[4][4];
    #pragma unroll
    for (int nt = 0; nt < 4; ++nt) {
        int j = wave * 64 + nt * 16 + (lane & 15);
        #pragma unroll
        for (int ks = 0; ks < 4; ++ks)
            bw[nt][ks] = *(const short8*)((const char*)W1abT + j * 256 + ks * 64 + (lane >> 4) * 16);
    }
    __syncthreads();

    f32x4 acc[2][4] = {};
    #pragma unroll
    for (int ks = 0; ks < 4; ++ks) {
        short8 a[2];
        #pragma unroll
        for (int mt = 0; mt < 2; ++mt) {
            int row = mt * 16 + (lane & 15);
            int byteoff = row * 256 + (((ks * 64) + ((lane >> 4) * 16)) ^ ((row & 7) << 4));
            a[mt] = *(short8*)((char*)hs + byteoff);
        }
        #pragma unroll
        for (int mt = 0; mt < 2; ++mt)
            #pragma unroll
            for (int nt = 0; nt < 4; ++nt)
                acc[mt][nt] = __builtin_amdgcn_mfma_f32_16x16x32_bf16(a[mt], bw[nt][ks], acc[mt][nt], 0, 0, 0);
    }

    #pragma unroll
    for (int mt = 0; mt < 2; ++mt) {
        #pragma unroll
        for (int nt = 0; nt < 4; ++nt) {
            int j = wave * 64 + nt * 16 + (lane & 15);
            float bias = (j < 128) ? b1[j] : 0.f;
            #pragma unroll
            for (int r = 0; r < 4; ++r) {
                int node = n0 + mt * 16 + (lane >> 4) * 4 + r;
                if (node < N) AB[(size_t)node * 256 + j] = f2bf(acc[mt][nt][r] + bias);
            }
        }
    }
}

// ---------------- kernel 2: barrier-free wave-autonomous edge MLP + scatter ----------------
// Each wave owns 16-edge tiles; gather produces MFMA A-fragments directly.
// __launch_bounds__(256,4): cap VGPR at 128 -> 4 waves/SIMD (occupancy was the
// r4 bottleneck at 160 VGPR / 2 waves/SIMD). Loop-invariant constant arrays
// live in LDS so the allocator can rematerialize instead of spilling.
__global__ __launch_bounds__(256, 4) void edge_kernel(
        const u16* __restrict__ AB, const u16* __restrict__ W2T,
        const int* __restrict__ eidx, const float* __restrict__ coord_diff,
        const float* __restrict__ edge_attr, const float* __restrict__ edge_mask,
        const float* __restrict__ W1, const float* __restrict__ b2,
        const float* __restrict__ W3, float* __restrict__ agg, int E) {
    __shared__ u16 w2s[128 * 128];   // swizzled W2T copy (32 KB)
    __shared__ float ssc[4][16];     // per-wave scale scratch
    __shared__ float sw1c[128];      // W1 edge_attr row
    __shared__ float sb2[128];
    __shared__ float sw3[128];

    const int tid = threadIdx.x;
    const int lane = tid & 63;
    const int wv = tid >> 6;
    const int le = lane & 15;        // edge-sub (A rows) / col-sub (B cols)
    const int lg = lane >> 4;        // k-chunk group 0..3

    // stage W2T -> LDS, swizzled: byte ^= (row&7)<<4
    #pragma unroll
    for (int it = 0; it < 8; ++it) {
        int idx = it * 256 + tid;        // 2048 x 16B = 32 KB
        int j = idx >> 4, c16 = idx & 15;
        uint4 v = *(const uint4*)((const char*)W2T + idx * 16);
        *(uint4*)((char*)w2s + j * 256 + ((c16 * 16) ^ ((j & 7) << 4))) = v;
    }
    if (tid < 128) {
        sw1c[tid] = W1[256 * 128 + tid];
        sb2[tid]  = b2[tid];
        sw3[tid]  = W3[tid];
    }
    __syncthreads();                  // LDS tables ready (only barrier in kernel)

    const int ntiles = (E + 15) >> 4;
    const int wpb = blockDim.x >> 6;
    const int nwaves = gridDim.x * wpb;
    int tile = blockIdx.x * wpb + wv;
    if (tile >= ntiles) return;

    // ---- prologue: meta(t0) + gather(t0)
    int e0 = tile << 4;
    int epc = min(e0 + le, E - 1);
    int rowc = eidx[epc];
    int colc = eidx[E + epc];
    float eac = edge_attr[epc];
    float eml = edge_mask[epc];
    float cdl = coord_diff[min(e0 * 3 + lane, E * 3 - 1)];

    uint4 va[4], vb[4];
    {
        const char* rp = (const char*)(AB + (size_t)rowc * 256);
        const char* cp = (const char*)(AB + (size_t)colc * 256 + 128);
        #pragma unroll
        for (int ks = 0; ks < 4; ++ks) {
            va[ks] = *(const uint4*)(rp + ks * 64 + lg * 16);
            vb[ks] = *(const uint4*)(cp + ks * 64 + lg * 16);
        }
    }

    while (true) {
        int next = tile + nwaves;
        bool hn = next < ntiles;
        int nb = hn ? next : tile;
        int ne0 = nb << 4;

        // issue meta(next) early (broadcast/coalesced; hides under convert)
        int nepc = min(ne0 + le, E - 1);
        int rown = eidx[nepc];
        int coln = eidx[E + nepc];
        float ean = edge_attr[nepc];
        float emn = edge_mask[nepc];
        float cdn = coord_diff[min(ne0 * 3 + lane, E * 3 - 1)];

        // convert current gathers -> A-fragments (layer-1 finish + silu, in regs)
        short8 pa[4];
        #pragma unroll
        for (int ks = 0; ks < 4; ++ks) {
            union { u32 w[4]; short8 s; } u;
            #pragma unroll
            for (int jp = 0; jp < 4; ++jp) {
                float2 wc = *(const float2*)&sw1c[ks * 32 + lg * 8 + 2 * jp];
                u32 ua = ((const u32*)&va[ks])[jp];
                u32 ub = ((const u32*)&vb[ks])[jp];
                float p0 = bflo(ua) + bflo(ub) + eac * wc.x;
                float p1 = bfhi(ua) + bfhi(ub) + eac * wc.y;
                float x0 = silu(p0), x1 = silu(p1);
                u.w[jp] = __builtin_amdgcn_perm(__float_as_uint(x1), __float_as_uint(x0), 0x07060302);
            }
            pa[ks] = u.s;
        }

        // issue gather(next) into va/vb (latency hides under MFMA + epilogue)
        if (hn) {
            const char* rp = (const char*)(AB + (size_t)rown * 256);
            const char* cp = (const char*)(AB + (size_t)coln * 256 + 128);
            #pragma unroll
            for (int ks = 0; ks < 4; ++ks) {
                va[ks] = *(const uint4*)(rp + ks * 64 + lg * 16);
                vb[ks] = *(const uint4*)(cp + ks * 64 + lg * 16);
            }
        }

        // layer 2: x2 = X1 @ W2  (B-frags from swizzled LDS, ~2-way conflicts)
        f32x4 acc[8] = {};
        #pragma unroll
        for (int ks = 0; ks < 4; ++ks) {
            #pragma unroll
            for (int nt = 0; nt < 8; ++nt) {
                int row = nt * 16 + le;
                const short8 bwf = *(const short8*)((const char*)w2s +
                        row * 256 + (((ks * 64) + lg * 16) ^ ((le & 7) << 4)));
                acc[nt] = __builtin_amdgcn_mfma_f32_16x16x32_bf16(pa[ks], bwf, acc[nt], 0, 0, 0);
            }
        }

        // epilogue: scale[edge] = sum_c silu(x2+b2)*W3  (b2/W3 from LDS)
        float s[4];
        #pragma unroll
        for (int r = 0; r < 4; ++r) {
            float t = 0.f;
            #pragma unroll
            for (int nt = 0; nt < 8; ++nt)
                t += silu(acc[nt][r] + sb2[nt * 16 + le]) * sw3[nt * 16 + le];
            t += __shfl_xor(t, 1);
            t += __shfl_xor(t, 2);
            t += __shfl_xor(t, 4);
            t += __shfl_xor(t, 8);
            s[r] = t;                 // edge lg*4+r, valid at le==0
        }
        if (le == 0) {
            f32x4 sv = { s[0], s[1], s[2], s[3] };
            *(f32x4*)&ssc[wv][lg * 4] = sv;   // same-wave LDS, lgkmcnt-ordered
        }

        // scatter: 3 atomics per edge (lanes 0..47)
        int els = (lane < 48) ? (lane / 3) : 0;
        int rA = __shfl(rowc, els);
        float emA = __shfl(eml, els);
        float sc = ssc[wv][els];
        if (lane < 48 && (e0 + els) < E)
            atomicAdd(&agg[rA * 3 + (lane - els * 3)], cdl * emA * sc);

        if (!hn) break;
        tile = next; e0 = ne0;
        rowc = rown; colc = coln; eac = ean; eml = emn; cdl = cdn;
    }
}

// ---------------- kernel 3: coord update ----------------
__global__ void finalize(const float* __restrict__ coord, const float* __restrict__ agg,
                         const float* __restrict__ node_mask, float* __restrict__ out, int n3) {
    int i = blockIdx.x * blockDim.x + threadIdx.x;
    if (i < n3) {
        int n = i / 3;
        out[i] = (coord[i] + agg[i] * NORM_INV) * node_mask[n];
    }
}

extern "C" void kernel_launch(void* const* d_in, const int* in_sizes, int n_in,
                              void* d_out, int out_size, void* d_ws, size_t ws_size,
                              hipStream_t stream) {
    const float* h          = (const float*)d_in[0];
    const float* coord      = (const float*)d_in[1];
    const int*   eidx       = (const int*)d_in[2];
    const float* coord_diff = (const float*)d_in[3];
    const float* edge_attr  = (const float*)d_in[4];
    const float* node_mask  = (const float*)d_in[5];
    const float* edge_mask  = (const float*)d_in[6];
    const float* W1         = (const float*)d_in[7];
    const float* b1         = (const float*)d_in[8];
    const float* W2         = (const float*)d_in[9];
    const float* b2         = (const float*)d_in[10];
    const float* W3         = (const float*)d_in[11];

    int N = in_sizes[0] / 128;   // 50000
    int E = in_sizes[2] / 2;     // 800000

    char* ws = (char*)d_ws;
    size_t off = 0;
    u16* AB    = (u16*)(ws + off); off += (size_t)N * 256 * sizeof(u16); off = (off + 255) & ~(size_t)255;
    u16* W1abT = (u16*)(ws + off); off += 256 * 128 * sizeof(u16);
    u16* W2T   = (u16*)(ws + off); off += 128 * 128 * sizeof(u16);
    float* agg = (float*)(ws + off); off += (size_t)N * 3 * sizeof(float);

    hipMemsetAsync(agg, 0, (size_t)N * 3 * sizeof(float), stream);
    hipLaunchKernelGGL(prep_weights, dim3(192), dim3(256), 0, stream, W1, W2, W1abT, W2T);
    hipLaunchKernelGGL(ab_kernel, dim3((N + 31) / 32), dim3(256), 0, stream, h, b1, W1abT, AB, N);
    hipLaunchKernelGGL(edge_kernel, dim3(1024), dim3(256), 0, stream,
                       AB, W2T, eidx, coord_diff, edge_attr, edge_mask, W1, b2, W3, agg, E);
    int n3 = N * 3;
    hipLaunchKernelGGL(finalize, dim3((n3 + 255) / 256), dim3(256), 0, stream,
                       coord, agg, node_mask, (float*)d_out, n3);
}

// Round 6
// 173.192 us; speedup vs baseline: 3.2627x; 3.2627x over previous
//
#include <hip/hip_runtime.h>
#include <hip/hip_bf16.h>

typedef __attribute__((ext_vector_type(8))) short short8;
typedef __attribute__((ext_vector_type(4))) float f32x4;
typedef unsigned short u16;
typedef unsigned int u32;

#define NORM_INV (1.0f / 100.0f)

__device__ __forceinline__ float silu(float x) {
    return x * __builtin_amdgcn_rcpf(1.0f + __expf(-x));
}

__device__ __forceinline__ u16 f2bf(float x) {
    union { float f; u32 u; } v; v.f = x;
    u32 r = v.u + 0x7fff + ((v.u >> 16) & 1);   // RNE
    return (u16)(r >> 16);
}

__device__ __forceinline__ float bflo(u32 u) {
    union { u32 u; float f; } v; v.u = u << 16; return v.f;
}
__device__ __forceinline__ float bfhi(u32 u) {
    union { u32 u; float f; } v; v.u = u & 0xffff0000u; return v.f;
}

// ---------------- kernel 0: weight transposes (tiny) ----------------
__global__ void prep_weights(const float* __restrict__ W1, const float* __restrict__ W2,
                             u16* __restrict__ W1abT, u16* __restrict__ W2T) {
    int idx = blockIdx.x * blockDim.x + threadIdx.x;
    if (idx < 256 * 128) {
        int j = idx >> 7, k = idx & 127;
        float v = (j < 128) ? W1[k * 128 + j] : W1[(128 + k) * 128 + (j - 128)];
        W1abT[j * 128 + k] = f2bf(v);
    } else if (idx < 256 * 128 + 128 * 128) {
        int t = idx - 256 * 128;
        int n = t >> 7, k = t & 127;
        W2T[n * 128 + k] = f2bf(W2[k * 128 + n]);
    }
}

// ---------------- kernel 1: AB[node][256] = [h@W1a + b1 | h@W1b] ----------------
__global__ __launch_bounds__(256) void ab_kernel(const float* __restrict__ h,
        const float* __restrict__ b1, const u16* __restrict__ W1abT,
        u16* __restrict__ AB, int N) {
    __shared__ u16 hs[32 * 128];     // 32 nodes x 128 k, bf16, XOR-swizzled
    int tid = threadIdx.x;
    int n0 = blockIdx.x * 32;
    int lane = tid & 63, wave = tid >> 6;

    #pragma unroll
    for (int it = 0; it < 8; ++it) {
        int item = it * 256 + tid;          // 2048 items, 2 k each
        int m = item >> 6;
        int k = (item & 63) * 2;
        float2 hv = make_float2(0.f, 0.f);
        if (n0 + m < N) hv = *(const float2*)(h + (size_t)(n0 + m) * 128 + k);
        u32 pk = (u32)f2bf(hv.x) | ((u32)f2bf(hv.y) << 16);
        int byteoff = m * 256 + ((k * 2) ^ ((m & 7) << 4));
        *(u32*)((char*)hs + byteoff) = pk;
    }

    short8 bw[4][4];
    #pragma unroll
    for (int nt = 0; nt < 4; ++nt) {
        int j = wave * 64 + nt * 16 + (lane & 15);
        #pragma unroll
        for (int ks = 0; ks < 4; ++ks)
            bw[nt][ks] = *(const short8*)((const char*)W1abT + j * 256 + ks * 64 + (lane >> 4) * 16);
    }
    __syncthreads();

    f32x4 acc[2][4] = {};
    #pragma unroll
    for (int ks = 0; ks < 4; ++ks) {
        short8 a[2];
        #pragma unroll
        for (int mt = 0; mt < 2; ++mt) {
            int row = mt * 16 + (lane & 15);
            int byteoff = row * 256 + (((ks * 64) + ((lane >> 4) * 16)) ^ ((row & 7) << 4));
            a[mt] = *(short8*)((char*)hs + byteoff);
        }
        #pragma unroll
        for (int mt = 0; mt < 2; ++mt)
            #pragma unroll
            for (int nt = 0; nt < 4; ++nt)
                acc[mt][nt] = __builtin_amdgcn_mfma_f32_16x16x32_bf16(a[mt], bw[nt][ks], acc[mt][nt], 0, 0, 0);
    }

    #pragma unroll
    for (int mt = 0; mt < 2; ++mt) {
        #pragma unroll
        for (int nt = 0; nt < 4; ++nt) {
            int j = wave * 64 + nt * 16 + (lane & 15);
            float bias = (j < 128) ? b1[j] : 0.f;
            #pragma unroll
            for (int r = 0; r < 4; ++r) {
                int node = n0 + mt * 16 + (lane >> 4) * 4 + r;
                if (node < N) AB[(size_t)node * 256 + j] = f2bf(acc[mt][nt][r] + bias);
            }
        }
    }
}

// ---------------- kernel 2: barrier-free wave-autonomous edge MLP + scatter ----------------
// Each wave owns 16-edge tiles; gather produces MFMA A-fragments directly.
// Single-assignment pipeline: convert drains va/vb -> pa, then next tile's
// gather writes the SAME va/vb registers (one gather buffer live, not two).
// No forced occupancy bound (r5 lesson: forcing 4 blocks/CU -> 64 VGPR -> spills).
__global__ __launch_bounds__(256) void edge_kernel(
        const u16* __restrict__ AB, const u16* __restrict__ W2T,
        const int* __restrict__ eidx, const float* __restrict__ coord_diff,
        const float* __restrict__ edge_attr, const float* __restrict__ edge_mask,
        const float* __restrict__ W1, const float* __restrict__ b2,
        const float* __restrict__ W3, float* __restrict__ agg, int E) {
    __shared__ u16 w2s[128 * 128];   // swizzled W2T copy (32 KB)
    __shared__ float ssc[4][16];     // per-wave scale scratch
    __shared__ float sw1c[128];      // W1 edge_attr row
    __shared__ float sb2[128];
    __shared__ float sw3[128];

    const int tid = threadIdx.x;
    const int lane = tid & 63;
    const int wv = tid >> 6;
    const int le = lane & 15;        // edge-sub (A rows) / col-sub (B cols)
    const int lg = lane >> 4;        // k-chunk group 0..3

    // stage W2T -> LDS, swizzled: byte ^= (row&7)<<4
    #pragma unroll
    for (int it = 0; it < 8; ++it) {
        int idx = it * 256 + tid;        // 2048 x 16B = 32 KB
        int j = idx >> 4, c16 = idx & 15;
        uint4 v = *(const uint4*)((const char*)W2T + idx * 16);
        *(uint4*)((char*)w2s + j * 256 + ((c16 * 16) ^ ((j & 7) << 4))) = v;
    }
    if (tid < 128) {
        sw1c[tid] = W1[256 * 128 + tid];
        sb2[tid]  = b2[tid];
        sw3[tid]  = W3[tid];
    }
    __syncthreads();                  // LDS tables ready (only barrier in kernel)

    const int ntiles = (E + 15) >> 4;
    const int wpb = blockDim.x >> 6;
    const int nwaves = gridDim.x * wpb;
    int tile = blockIdx.x * wpb + wv;
    if (tile >= ntiles) return;

    // ---- prologue: meta(t0) + gather(t0)
    int e0 = tile << 4;
    int epc = min(e0 + le, E - 1);
    int rowc = eidx[epc];
    int colc = eidx[E + epc];
    float eac = edge_attr[epc];
    float eml = edge_mask[epc];
    float cdl = coord_diff[min(e0 * 3 + lane, E * 3 - 1)];

    uint4 va[4], vb[4];
    {
        const char* rp = (const char*)(AB + (size_t)rowc * 256);
        const char* cp = (const char*)(AB + (size_t)colc * 256 + 128);
        #pragma unroll
        for (int ks = 0; ks < 4; ++ks) {
            va[ks] = *(const uint4*)(rp + ks * 64 + lg * 16);
            vb[ks] = *(const uint4*)(cp + ks * 64 + lg * 16);
        }
    }

    while (true) {
        int next = tile + nwaves;
        bool hn = next < ntiles;
        int nb = hn ? next : tile;
        int ne0 = nb << 4;

        // issue meta(next) early (broadcast/coalesced; hides under convert)
        int nepc = min(ne0 + le, E - 1);
        int rown = eidx[nepc];
        int coln = eidx[E + nepc];
        float ean = edge_attr[nepc];
        float emn = edge_mask[nepc];
        float cdn = coord_diff[min(ne0 * 3 + lane, E * 3 - 1)];

        // convert current gathers -> A-fragments; va/vb are DEAD afterwards
        short8 pa[4];
        #pragma unroll
        for (int ks = 0; ks < 4; ++ks) {
            union { u32 w[4]; short8 s; } u;
            #pragma unroll
            for (int jp = 0; jp < 4; ++jp) {
                float2 wc = *(const float2*)&sw1c[ks * 32 + lg * 8 + 2 * jp];
                u32 ua = ((const u32*)&va[ks])[jp];
                u32 ub = ((const u32*)&vb[ks])[jp];
                float p0 = bflo(ua) + bflo(ub) + eac * wc.x;
                float p1 = bfhi(ua) + bfhi(ub) + eac * wc.y;
                float x0 = silu(p0), x1 = silu(p1);
                u.w[jp] = __builtin_amdgcn_perm(__float_as_uint(x1), __float_as_uint(x0), 0x07060302);
            }
            pa[ks] = u.s;
        }

        // gather(next) re-uses the SAME va/vb registers (latency hides under MFMA)
        if (hn) {
            const char* rp = (const char*)(AB + (size_t)rown * 256);
            const char* cp = (const char*)(AB + (size_t)coln * 256 + 128);
            #pragma unroll
            for (int ks = 0; ks < 4; ++ks) {
                va[ks] = *(const uint4*)(rp + ks * 64 + lg * 16);
                vb[ks] = *(const uint4*)(cp + ks * 64 + lg * 16);
            }
        }

        // layer 2: x2 = X1 @ W2  (B-frags from swizzled LDS, ~2-way conflicts)
        f32x4 acc[8] = {};
        #pragma unroll
        for (int ks = 0; ks < 4; ++ks) {
            #pragma unroll
            for (int nt = 0; nt < 8; ++nt) {
                int row = nt * 16 + le;
                const short8 bwf = *(const short8*)((const char*)w2s +
                        row * 256 + (((ks * 64) + lg * 16) ^ ((le & 7) << 4)));
                acc[nt] = __builtin_amdgcn_mfma_f32_16x16x32_bf16(pa[ks], bwf, acc[nt], 0, 0, 0);
            }
        }

        // epilogue: scale[edge] = sum_c silu(x2+b2)*W3  (b2/W3 from LDS)
        float s[4];
        #pragma unroll
        for (int r = 0; r < 4; ++r) {
            float t = 0.f;
            #pragma unroll
            for (int nt = 0; nt < 8; ++nt)
                t += silu(acc[nt][r] + sb2[nt * 16 + le]) * sw3[nt * 16 + le];
            t += __shfl_xor(t, 1);
            t += __shfl_xor(t, 2);
            t += __shfl_xor(t, 4);
            t += __shfl_xor(t, 8);
            s[r] = t;                 // edge lg*4+r, valid at le==0
        }
        if (le == 0) {
            f32x4 sv = { s[0], s[1], s[2], s[3] };
            *(f32x4*)&ssc[wv][lg * 4] = sv;   // same-wave LDS, lgkmcnt-ordered
        }

        // scatter: 3 atomics per edge (lanes 0..47)
        int els = (lane < 48) ? (lane / 3) : 0;
        int rA = __shfl(rowc, els);
        float emA = __shfl(eml, els);
        float sc = ssc[wv][els];
        if (lane < 48 && (e0 + els) < E)
            atomicAdd(&agg[rA * 3 + (lane - els * 3)], cdl * emA * sc);

        if (!hn) break;
        tile = next; e0 = ne0;
        rowc = rown; colc = coln; eac = ean; eml = emn; cdl = cdn;
    }
}

// ---------------- kernel 3: coord update ----------------
__global__ void finalize(const float* __restrict__ coord, const float* __restrict__ agg,
                         const float* __restrict__ node_mask, float* __restrict__ out, int n3) {
    int i = blockIdx.x * blockDim.x + threadIdx.x;
    if (i < n3) {
        int n = i / 3;
        out[i] = (coord[i] + agg[i] * NORM_INV) * node_mask[n];
    }
}

extern "C" void kernel_launch(void* const* d_in, const int* in_sizes, int n_in,
                              void* d_out, int out_size, void* d_ws, size_t ws_size,
                              hipStream_t stream) {
    const float* h          = (const float*)d_in[0];
    const float* coord      = (const float*)d_in[1];
    const int*   eidx       = (const int*)d_in[2];
    const float* coord_diff = (const float*)d_in[3];
    const float* edge_attr  = (const float*)d_in[4];
    const float* node_mask  = (const float*)d_in[5];
    const float* edge_mask  = (const float*)d_in[6];
    const float* W1         = (const float*)d_in[7];
    const float* b1         = (const float*)d_in[8];
    const float* W2         = (const float*)d_in[9];
    const float* b2         = (const float*)d_in[10];
    const float* W3         = (const float*)d_in[11];

    int N = in_sizes[0] / 128;   // 50000
    int E = in_sizes[2] / 2;     // 800000

    char* ws = (char*)d_ws;
    size_t off = 0;
    u16* AB    = (u16*)(ws + off); off += (size_t)N * 256 * sizeof(u16); off = (off + 255) & ~(size_t)255;
    u16* W1abT = (u16*)(ws + off); off += 256 * 128 * sizeof(u16);
    u16* W2T   = (u16*)(ws + off); off += 128 * 128 * sizeof(u16);
    float* agg = (float*)(ws + off); off += (size_t)N * 3 * sizeof(float);

    hipMemsetAsync(agg, 0, (size_t)N * 3 * sizeof(float), stream);
    hipLaunchKernelGGL(prep_weights, dim3(192), dim3(256), 0, stream, W1, W2, W1abT, W2T);
    hipLaunchKernelGGL(ab_kernel, dim3((N + 31) / 32), dim3(256), 0, stream, h, b1, W1abT, AB, N);
    hipLaunchKernelGGL(edge_kernel, dim3(1024), dim3(256), 0, stream,
                       AB, W2T, eidx, coord_diff, edge_attr, edge_mask, W1, b2, W3, agg, E);
    int n3 = N * 3;
    hipLaunchKernelGGL(finalize, dim3((n3 + 255) / 256), dim3(256), 0, stream,
                       coord, agg, node_mask, (float*)d_out, n3);
}